// Round 1
// baseline (323.596 us; speedup 1.0000x reference)
//
#include <hip/hip_runtime.h>
#include <hip/hip_bf16.h>
#include <stdint.h>

#define B_ 4
#define N_ 2048
#define D_ 1024
#define K_ 16
#define MROWS (B_*N_)      // 8192
#define NC_ 32
#define CLEN_ (N_/NC_)     // 64

typedef unsigned short u16;
typedef __attribute__((ext_vector_type(8))) short bf16x8;
typedef __attribute__((ext_vector_type(4))) float f32x4;

__device__ __forceinline__ u16 f2bf(float f) {
  uint32_t u = __float_as_uint(f);
  u = u + 0x7fffu + ((u >> 16) & 1u);
  return (u16)(u >> 16);
}

// ---------------- cast fp32 -> bf16 (vectorized) ----------------
__global__ __launch_bounds__(256) void cast_kernel(const float* __restrict__ in,
                                                   u16* __restrict__ out, int n) {
  int i = (blockIdx.x * 256 + threadIdx.x) * 4;
  if (i >= n) return;
  float4 v = *(const float4*)(in + i);
  ushort4 o;
  o.x = f2bf(v.x); o.y = f2bf(v.y); o.z = f2bf(v.z); o.w = f2bf(v.w);
  *(ushort4*)(out + i) = o;
}

// ---------------- bf16 GEMM, C[m,n] = sum_k A[m,k]*W[n,k] ----------------
// m97 structure: 128x128 tile, 4 waves (2x2 of 64x64), BK=32, global_load_lds w=16.
// epi: 0 = plain fp32 store, 1 = f-gate activation exp(logsigmoid(v)/16)
__global__ __launch_bounds__(256) void gemm_bt(const u16* __restrict__ A,
                                               const u16* __restrict__ W,
                                               float* __restrict__ C,
                                               int M, int N, int K, int epi) {
  __shared__ u16 As[128 * 32];
  __shared__ u16 Bs[128 * 32];
  const int tid = threadIdx.x;
  const int w = tid >> 6, l = tid & 63;
  const int nbn = N >> 7;
  const int bm = blockIdx.x / nbn, bn = blockIdx.x % nbn;
  const int wm = (w >> 1) * 64, wn = (w & 1) * 64;
  const int lr = l & 15, lk = (l >> 4) * 8;

  f32x4 acc[4][4] = {};

  for (int kt = 0; kt < K; kt += 32) {
#pragma unroll
    for (int j = 0; j < 2; ++j) {
      int ofs = w * 1024 + j * 4096;        // wave-uniform byte offset into 8KB tile
      int gofs = ofs + l * 16;              // this lane's byte offset
      int row = gofs >> 6;                  // 64 B per row (32 bf16)
      int ke = (gofs & 63) >> 1;            // element offset within row
      const u16* ga = A + (size_t)(bm * 128 + row) * K + kt + ke;
      const u16* gb = W + (size_t)(bn * 128 + row) * K + kt + ke;
      __builtin_amdgcn_global_load_lds(
          (const __attribute__((address_space(1))) void*)ga,
          (__attribute__((address_space(3))) void*)((char*)As + ofs), 16, 0, 0);
      __builtin_amdgcn_global_load_lds(
          (const __attribute__((address_space(1))) void*)gb,
          (__attribute__((address_space(3))) void*)((char*)Bs + ofs), 16, 0, 0);
    }
    __syncthreads();
    bf16x8 af[4], bfr[4];
#pragma unroll
    for (int i2 = 0; i2 < 4; ++i2) {
      af[i2]  = *(const bf16x8*)&As[(wm + i2 * 16 + lr) * 32 + lk];
      bfr[i2] = *(const bf16x8*)&Bs[(wn + i2 * 16 + lr) * 32 + lk];
    }
#pragma unroll
    for (int i2 = 0; i2 < 4; ++i2)
#pragma unroll
      for (int j2 = 0; j2 < 4; ++j2)
        acc[i2][j2] = __builtin_amdgcn_mfma_f32_16x16x32_bf16(af[i2], bfr[j2], acc[i2][j2], 0, 0, 0);
    __syncthreads();
  }

  const int orow0 = bm * 128 + wm + (l >> 4) * 4;
  const int ocol0 = bn * 128 + wn + (l & 15);
#pragma unroll
  for (int i2 = 0; i2 < 4; ++i2) {
#pragma unroll
    for (int j2 = 0; j2 < 4; ++j2) {
#pragma unroll
      for (int r = 0; r < 4; ++r) {
        int row = orow0 + i2 * 16 + r;
        int col = ocol0 + j2 * 16;
        float v = acc[i2][j2][r];
        if (epi == 1) {
          float ls = (v >= 0.0f) ? -log1pf(expf(-v)) : (v - log1pf(expf(v)));
          v = expf(ls * (1.0f / 16.0f));
        }
        C[(size_t)row * N + col] = v;
      }
    }
  }
}

// ---------------- e/s projections: [8192,1024] x [16,1024]^T (fp32) ----------------
__global__ __launch_bounds__(256) void es_proj(const float* __restrict__ x,
                                               const float* __restrict__ We,
                                               const float* __restrict__ Ws,
                                               float* __restrict__ e,
                                               float* __restrict__ s) {
  int row = blockIdx.x * 4 + (threadIdx.x >> 6);
  int l = threadIdx.x & 63;
  const float* xr = x + (size_t)row * D_;
  float4 xv[4];
#pragma unroll
  for (int j = 0; j < 4; ++j) xv[j] = *(const float4*)(xr + j * 256 + l * 4);
  float pe[K_], ps[K_];
#pragma unroll
  for (int k = 0; k < K_; ++k) {
    float ae = 0.f, as_ = 0.f;
#pragma unroll
    for (int j = 0; j < 4; ++j) {
      float4 wv = *(const float4*)(We + (size_t)k * D_ + j * 256 + l * 4);
      float4 sv = *(const float4*)(Ws + (size_t)k * D_ + j * 256 + l * 4);
      ae  += xv[j].x * wv.x + xv[j].y * wv.y + xv[j].z * wv.z + xv[j].w * wv.w;
      as_ += xv[j].x * sv.x + xv[j].y * sv.y + xv[j].z * sv.z + xv[j].w * sv.w;
    }
    pe[k] = ae; ps[k] = as_;
  }
#pragma unroll
  for (int k = 0; k < K_; ++k) {
    float ae = pe[k], as_ = ps[k];
    for (int off = 32; off > 0; off >>= 1) {
      ae  += __shfl_down(ae, off);
      as_ += __shfl_down(as_, off);
    }
    if (l == 0) {
      e[(size_t)row * K_ + k] = ae;
      s[(size_t)row * K_ + k] = as_;
    }
  }
}

// ---------------- scan pass1: per-chunk zero-start scan -> A_c, P_c ----------------
__global__ __launch_bounds__(256) void scan_pass1(const float* __restrict__ ibuf,
                                                  const float* __restrict__ fbuf,
                                                  const float* __restrict__ ebuf,
                                                  float* __restrict__ Asc,
                                                  float* __restrict__ Psc) {
  int bid = blockIdx.x;
  int dq = bid & 3, c = (bid >> 2) & (NC_ - 1), b = bid >> 7;
  int d = dq * 256 + threadIdx.x;
  int t0 = c * CLEN_;
  float m[K_];
#pragma unroll
  for (int k = 0; k < K_; ++k) m[k] = 0.f;
  float p = 1.0f;
  const float* ip = ibuf + ((size_t)b * N_ + t0) * D_ + d;
  const float* fp = fbuf + ((size_t)b * N_ + t0) * D_ + d;
  const float* ep = ebuf + ((size_t)b * N_ + t0) * K_;
  for (int t = 0; t < CLEN_; ++t) {
    float it = ip[(size_t)t * D_];
    float ft = fp[(size_t)t * D_];
    p *= ft;
#pragma unroll
    for (int k = 0; k < K_; ++k) m[k] = ft * m[k] + ep[t * K_ + k] * it;
  }
  float* ap = Asc + (((size_t)b * NC_ + c) * K_) * D_ + d;
#pragma unroll
  for (int k = 0; k < K_; ++k) ap[(size_t)k * D_] = m[k];
  Psc[((size_t)b * NC_ + c) * D_ + d] = p;
}

// ---------------- scan pass2: sequential inter-chunk combine ----------------
__global__ __launch_bounds__(256) void scan_pass2(const float* __restrict__ Asc,
                                                  const float* __restrict__ Psc,
                                                  float* __restrict__ Ssc) {
  int idx = blockIdx.x * 256 + threadIdx.x;   // (b,k,d) over 65536
  int d = idx & (D_ - 1);
  int k = (idx >> 10) & (K_ - 1);
  int b = idx >> 14;
  float M = 0.f;
  for (int c = 0; c < NC_; ++c) {
    size_t base = (((size_t)b * NC_ + c) * K_ + k) * D_ + d;
    float a = Asc[base];
    float pp = Psc[((size_t)b * NC_ + c) * D_ + d];
    Ssc[base] = M;
    M = pp * M + a;
  }
}

// ---------------- scan pass3: replay chunk with init state, emit y (in-place into ibuf) ----------------
__global__ __launch_bounds__(256) void scan_pass3(float* __restrict__ ibuf,
                                                  const float* __restrict__ fbuf,
                                                  const float* __restrict__ ebuf,
                                                  const float* __restrict__ sbuf,
                                                  const float* __restrict__ Ssc) {
  int bid = blockIdx.x;
  int dq = bid & 3, c = (bid >> 2) & (NC_ - 1), b = bid >> 7;
  int d = dq * 256 + threadIdx.x;
  int t0 = c * CLEN_;
  float m[K_];
  const float* sp0 = Ssc + (((size_t)b * NC_ + c) * K_) * D_ + d;
#pragma unroll
  for (int k = 0; k < K_; ++k) m[k] = sp0[(size_t)k * D_];
  float* ip = ibuf + ((size_t)b * N_ + t0) * D_ + d;
  const float* fp = fbuf + ((size_t)b * N_ + t0) * D_ + d;
  const float* ep = ebuf + ((size_t)b * N_ + t0) * K_;
  const float* zp = sbuf + ((size_t)b * N_ + t0) * K_;
  for (int t = 0; t < CLEN_; ++t) {
    float it = ip[(size_t)t * D_];
    float ft = fp[(size_t)t * D_];
    float y = 0.f;
#pragma unroll
    for (int k = 0; k < K_; ++k) {
      m[k] = ft * m[k] + ep[t * K_ + k] * it;
      y += zp[t * K_ + k] * m[k];
    }
    ip[(size_t)t * D_] = y;
  }
}

// ---------------- LayerNorm -> bf16 ----------------
__global__ __launch_bounds__(256) void ln_kernel(const float* __restrict__ y,
                                                 const float* __restrict__ gamma,
                                                 const float* __restrict__ beta,
                                                 u16* __restrict__ yn) {
  int row = blockIdx.x * 4 + (threadIdx.x >> 6);
  int l = threadIdx.x & 63;
  const float* yr = y + (size_t)row * D_;
  float4 v[4];
  float sum = 0.f;
#pragma unroll
  for (int j = 0; j < 4; ++j) {
    v[j] = *(const float4*)(yr + j * 256 + l * 4);
    sum += v[j].x + v[j].y + v[j].z + v[j].w;
  }
  for (int off = 32; off > 0; off >>= 1) sum += __shfl_xor(sum, off);
  float mu = sum * (1.0f / D_);
  float vs = 0.f;
#pragma unroll
  for (int j = 0; j < 4; ++j) {
    float dx = v[j].x - mu; vs += dx * dx;
    dx = v[j].y - mu; vs += dx * dx;
    dx = v[j].z - mu; vs += dx * dx;
    dx = v[j].w - mu; vs += dx * dx;
  }
  for (int off = 32; off > 0; off >>= 1) vs += __shfl_xor(vs, off);
  float rstd = rsqrtf(vs * (1.0f / D_) + 1e-5f);
#pragma unroll
  for (int j = 0; j < 4; ++j) {
    int col = j * 256 + l * 4;
    float4 g = *(const float4*)(gamma + col);
    float4 bt = *(const float4*)(beta + col);
    ushort4 o;
    o.x = f2bf((v[j].x - mu) * rstd * g.x + bt.x);
    o.y = f2bf((v[j].y - mu) * rstd * g.y + bt.y);
    o.z = f2bf((v[j].z - mu) * rstd * g.z + bt.z);
    o.w = f2bf((v[j].w - mu) * rstd * g.w + bt.w);
    *(ushort4*)(yn + (size_t)row * D_ + col) = o;
  }
}

extern "C" void kernel_launch(void* const* d_in, const int* in_sizes, int n_in,
                              void* d_out, int out_size, void* d_ws, size_t ws_size,
                              hipStream_t stream) {
  const float* x     = (const float*)d_in[0];
  const float* Wi    = (const float*)d_in[1];
  const float* We    = (const float*)d_in[2];
  const float* Wf    = (const float*)d_in[3];
  const float* Ws    = (const float*)d_in[4];
  const float* gamma = (const float*)d_in[5];
  const float* beta  = (const float*)d_in[6];
  const float* Wo    = (const float*)d_in[7];
  float* out = (float*)d_out;

  char* p = (char*)d_ws;
  u16* xb  = (u16*)p;  p += (size_t)MROWS * D_ * 2;       // 16 MB (reused as yn_bf16)
  u16* wib = (u16*)p;  p += (size_t)D_ * D_ * 2;          // 2 MB
  u16* wfb = (u16*)p;  p += (size_t)D_ * D_ * 2;          // 2 MB
  u16* wob = (u16*)p;  p += (size_t)D_ * D_ * 2;          // 2 MB
  float* ibuf = (float*)p; p += (size_t)MROWS * D_ * 4;   // 32 MB (i, then y in-place)
  float* fbuf = (float*)p; p += (size_t)MROWS * D_ * 4;   // 32 MB
  float* ebuf = (float*)p; p += (size_t)MROWS * K_ * 4;   // 512 KB
  float* sbuf = (float*)p; p += (size_t)MROWS * K_ * 4;   // 512 KB
  float* Asc  = (float*)p; p += (size_t)B_ * NC_ * K_ * D_ * 4;  // 8 MB
  float* Ssc  = (float*)p; p += (size_t)B_ * NC_ * K_ * D_ * 4;  // 8 MB
  float* Psc  = (float*)p; p += (size_t)B_ * NC_ * D_ * 4;       // 512 KB

  // 1. casts
  cast_kernel<<<MROWS * D_ / 1024, 256, 0, stream>>>(x, xb, MROWS * D_);
  cast_kernel<<<D_ * D_ / 1024, 256, 0, stream>>>(Wi, wib, D_ * D_);
  cast_kernel<<<D_ * D_ / 1024, 256, 0, stream>>>(Wf, wfb, D_ * D_);
  cast_kernel<<<D_ * D_ / 1024, 256, 0, stream>>>(Wo, wob, D_ * D_);

  // 2. big projections (bf16 MFMA)
  gemm_bt<<<(MROWS / 128) * (D_ / 128), 256, 0, stream>>>(xb, wib, ibuf, MROWS, D_, D_, 0);
  gemm_bt<<<(MROWS / 128) * (D_ / 128), 256, 0, stream>>>(xb, wfb, fbuf, MROWS, D_, D_, 1);

  // 3. e/s skinny projections (fp32)
  es_proj<<<MROWS / 4, 256, 0, stream>>>(x, We, Ws, ebuf, sbuf);

  // 4. chunked linear scan
  scan_pass1<<<B_ * NC_ * 4, 256, 0, stream>>>(ibuf, fbuf, ebuf, Asc, Psc);
  scan_pass2<<<B_ * K_ * D_ / 256, 256, 0, stream>>>(Asc, Psc, Ssc);
  scan_pass3<<<B_ * NC_ * 4, 256, 0, stream>>>(ibuf, fbuf, ebuf, sbuf, Ssc);

  // 5. LayerNorm -> bf16 (reuse xb)
  u16* ynb = xb;
  ln_kernel<<<MROWS / 4, 256, 0, stream>>>(ibuf, gamma, beta, ynb);

  // 6. output projection -> d_out
  gemm_bt<<<(MROWS / 128) * (D_ / 128), 256, 0, stream>>>(ynb, wob, out, MROWS, D_, D_, 0);
}